// Round 15
// baseline (52.476 us; speedup 1.0000x reference)
//
#include <hip/hip_runtime.h>
#include <math.h>

#define MA 64
#define ME 256
#define DM 256
#define DQK 32
#define ENVSTRIDE (MA * ME)            // 16384 floats per env
#define MASKVAL -998244352.0f          // bf16-rounded -1e9 (matches reference)
#define QK_SCALE 0.17677669529663687f  // 1/sqrt(32)
#define KSTR 40                        // LDS row stride in ushorts (80B)

typedef __attribute__((ext_vector_type(8))) short bf16x8;
typedef __attribute__((ext_vector_type(4))) float f32x4;
typedef unsigned short u16;

__device__ __forceinline__ int lb(const int* __restrict__ a, int n, int v){
  int lo = 0, hi = n;
  while (lo < hi){ int mid = (lo + hi) >> 1; if (a[mid] < v) lo = mid + 1; else hi = mid; }
  return lo;
}
// round-to-nearest-even f32 -> bf16 (validated rounds 8-14)
__device__ __forceinline__ unsigned pk2bf(float lo, float hi){
  unsigned ul = __float_as_uint(lo); ul = ul + 0x7FFFu + ((ul >> 16) & 1u);
  unsigned uh = __float_as_uint(hi); uh = uh + 0x7FFFu + ((uh >> 16) & 1u);
  return (ul >> 16) | (uh & 0xFFFF0000u);
}
__device__ __forceinline__ u16 f2bu(float f){
  unsigned u = __float_as_uint(f);
  return (u16)((u + 0x7FFFu + ((u >> 16) & 1u)) >> 16);
}

// ===== K0a: per-env ranges (r3-validated) =====
__global__ void ranges_kernel(const int* __restrict__ qindices, const int* __restrict__ kindices,
                              int A, int E, int B, int4* __restrict__ rng){
  int e = blockIdx.x * blockDim.x + threadIdx.x;
  if (e >= B) return;
  int qs = lb(qindices, A, e * MA);
  int qe = lb(qindices, A, e * MA + MA);
  int ks = lb(kindices, E, e * ME);
  int ke = lb(kindices, E, e * ME + ME);
  rng[e] = make_int4(qs, qe - qs, ks, ke - ks);
}

// ===== K0b: pack Wk|Wq into bf16 MFMA-fragment order (layout validated r10-r14) =====
__global__ __launch_bounds__(256)
void pack_w(const float* __restrict__ Wk, const float* __restrict__ Wq,
            unsigned* __restrict__ wfr_g){
  const int base = blockIdx.x * 512 + threadIdx.x;
  #pragma unroll
  for (int ii = 0; ii < 2; ++ii) {
    const int i = base + ii * 256;
    const int p = i & 3, ln = (i >> 2) & 63, nt = (i >> 8) & 1, kk = (i >> 9) & 7, wh = i >> 12;
    const int k0  = kk * 32 + (ln >> 4) * 8 + 2 * p;
    const int col = nt * 16 + (ln & 15);
    const float* W = wh ? Wq : Wk;
    wfr_g[i] = pk2bf(W[(size_t)k0 * DQK + col], W[(size_t)(k0 + 1) * DQK + col]);
  }
}

// ===== K1: fused per-env kernel (r10 datapath; serial chains removed) =====
__global__ __launch_bounds__(256)
void fused_env(const float* __restrict__ x,
               const float* __restrict__ bq, const float* __restrict__ bk,
               const int* __restrict__ actors, const int* __restrict__ qindices,
               const int* __restrict__ actees, const int* __restrict__ kindices,
               const int* __restrict__ prev_actions,
               const unsigned* __restrict__ wfr_g, const int4* __restrict__ rng,
               int A, int E, float* __restrict__ out)
{
  __shared__ __align__(16) unsigned wfr32[2 * 8 * 2 * 256];   // 32 KB packed W frags
  __shared__ u16 kb[ME * KSTR];    // 20 KB bf16 keys
  __shared__ u16 qsm[MA * KSTR];   //  5 KB bf16 queries

  const int t = threadIdx.x, b = blockIdx.x;
  const int lane = t & 63, w = t >> 6;
  const int lr = lane & 15, lq = lane >> 4;

  // ranges precomputed: one int4 broadcast load, no binary search, no extra barrier
  const int4 rg = rng[b];
  const int qstart = rg.x, qlen = rg.y, kstart = rg.z, klen = rg.w;

  // cooperative W-frag copy packed-global -> LDS (8 coalesced b128 per thread)
  {
    const float4* src = (const float4*)wfr_g;
    float4* dst = (float4*)wfr32;
    #pragma unroll
    for (int ii = 0; ii < 8; ++ii) dst[t + ii * 256] = src[t + ii * 256];
  }

  const float bkv0 = bk[lr], bkv1 = bk[16 + lr];
  const float bqv0 = bq[lr], bqv1 = bq[16 + lr];

  const int kt = (klen + 15) >> 4;
  const int qt = (qlen + 15) >> 4;
  const int ntiles = kt + qt;                       // <= 20
  const int nw = (ntiles > w) ? ((ntiles - w + 3) >> 2) : 0;   // tiles for this wave (<=5)

  // preload ALL tile gather-indices (independent loads, latency overlapped)
  int idxv[5];
  #pragma unroll
  for (int tt = 0; tt < 5; ++tt) {
    const int ic = min(w + 4 * tt, ntiles - 1);
    const bool isk = ic < kt;
    const int rbase = (isk ? ic : ic - kt) << 4;
    const int len   = isk ? klen : qlen;
    const int start = isk ? kstart : qstart;
    const int* gi   = isk ? actees : actors;
    idxv[tt] = gi[start + min(rbase + lr, len - 1)];
  }

  __syncthreads();   // wfr32 ready

  // ---- projection: fully unrolled tile loop (static idxv indices, r10 datapath) ----
  #pragma unroll
  for (int tt = 0; tt < 5; ++tt) {
    if (tt < nw) {
      const int i = w + 4 * tt;
      const bool isk = (i < kt);
      const int  rbase = isk ? (i << 4) : ((i - kt) << 4);
      const int  len   = isk ? klen : qlen;
      u16*       dst   = isk ? kb : qsm;
      const unsigned* fb = wfr32 + (isk ? 0 : 4096) + lane * 4;

      const float* xr = x + (size_t)idxv[tt] * DM + lq * 8;
      float4 cx[16];
      #pragma unroll
      for (int kk = 0; kk < 8; ++kk) {
        cx[2*kk]   = *(const float4*)(xr + kk * 32);
        cx[2*kk+1] = *(const float4*)(xr + kk * 32 + 4);
      }

      const float v0 = isk ? bkv0 : bqv0, v1 = isk ? bkv1 : bqv1;
      f32x4 a0 = {v0, v0, v0, v0}, a1 = {v1, v1, v1, v1};
      #pragma unroll
      for (int kk = 0; kk < 8; ++kk) {
        union { unsigned u[4]; bf16x8 v; } fa;
        fa.u[0] = pk2bf(cx[2*kk].x,   cx[2*kk].y);
        fa.u[1] = pk2bf(cx[2*kk].z,   cx[2*kk].w);
        fa.u[2] = pk2bf(cx[2*kk+1].x, cx[2*kk+1].y);
        fa.u[3] = pk2bf(cx[2*kk+1].z, cx[2*kk+1].w);
        const bf16x8 b0 = *(const bf16x8*)(fb + kk * 512);
        const bf16x8 b1 = *(const bf16x8*)(fb + kk * 512 + 256);
        a0 = __builtin_amdgcn_mfma_f32_16x16x32_bf16(fa.v, b0, a0, 0, 0, 0);
        a1 = __builtin_amdgcn_mfma_f32_16x16x32_bf16(fa.v, b1, a1, 0, 0, 0);
      }
      // D: col = lane&15, row = 4*(lane>>4)+reg (validated)
      #pragma unroll
      for (int reg = 0; reg < 4; ++reg) {
        const int row = rbase + 4 * lq + reg;
        if (row < len) {
          dst[row * KSTR + lr]      = f2bu(a0[reg]);
          dst[row * KSTR + 16 + lr] = f2bu(a1[reg]);
        }
      }
    }
  }
  __syncthreads();

  // ---- logits + softmax: wave w owns q rows 16w..16w+15 (validated r9/r10) ----
  float* out_lg = out + (size_t)3 * A + (size_t)b * ENVSTRIDE;
  const int row0 = 16 * w;

  if (row0 >= qlen) {          // fully padded rows: MASKVAL fill
    const float4 mv = make_float4(MASKVAL, MASKVAL, MASKVAL, MASKVAL);
    float4* o4 = (float4*)out_lg;
    #pragma unroll
    for (int rr = 0; rr < 16; ++rr) o4[(row0 + rr) * 64 + lane] = mv;
    return;
  }

  const bf16x8 afr = *(const bf16x8*)&qsm[(row0 + lr) * KSTR + lq * 8];
  f32x4 acc[16];
  #pragma unroll
  for (int nt = 0; nt < 16; ++nt) {
    const bf16x8 bfr2 = *(const bf16x8*)&kb[(16 * nt + lr) * KSTR + lq * 8];
    f32x4 z = {0.f, 0.f, 0.f, 0.f};
    acc[nt] = __builtin_amdgcn_mfma_f32_16x16x32_bf16(afr, bfr2, z, 0, 0, 0);
  }

  int par[4];
  float m[4], spa[4], es[4], ts[4];
  #pragma unroll
  for (int reg = 0; reg < 4; ++reg) {
    const int r = row0 + 4 * lq + reg;
    par[reg] = (r < qlen) ? (prev_actions[qstart + r] & (ME - 1)) : -1;
    m[reg] = MASKVAL; spa[reg] = MASKVAL; es[reg] = 0.f; ts[reg] = 0.f;
  }

  #pragma unroll
  for (int nt = 0; nt < 16; ++nt) {
    const int col = 16 * nt + lr;
    const bool kv = (col < klen);
    #pragma unroll
    for (int reg = 0; reg < 4; ++reg) {
      const float d = kv ? acc[nt][reg] * QK_SCALE : MASKVAL;
      acc[nt][reg] = d;
      m[reg] = fmaxf(m[reg], d);
      if (col == par[reg]) spa[reg] = d;
    }
  }
  #pragma unroll
  for (int off = 1; off < 16; off <<= 1) {
    #pragma unroll
    for (int reg = 0; reg < 4; ++reg) {
      m[reg]   = fmaxf(m[reg],   __shfl_xor(m[reg],   off));
      spa[reg] = fmaxf(spa[reg], __shfl_xor(spa[reg], off));
    }
  }
  #pragma unroll
  for (int nt = 0; nt < 16; ++nt) {
    #pragma unroll
    for (int reg = 0; reg < 4; ++reg) {
      const float dd = acc[nt][reg] - m[reg];
      if (dd > -80.f) { const float e = __expf(dd); es[reg] += e; ts[reg] += e * dd; }
    }
  }
  #pragma unroll
  for (int off = 1; off < 16; off <<= 1) {
    #pragma unroll
    for (int reg = 0; reg < 4; ++reg) {
      es[reg] += __shfl_xor(es[reg], off);
      ts[reg] += __shfl_xor(ts[reg], off);
    }
  }

  #pragma unroll
  for (int nt = 0; nt < 16; ++nt) {
    #pragma unroll
    for (int reg = 0; reg < 4; ++reg) {
      const int r = row0 + 4 * lq + reg;
      out_lg[r * ME + 16 * nt + lr] = (r < qlen) ? acc[nt][reg] : MASKVAL;
    }
  }
  if (lr == 0) {
    #pragma unroll
    for (int reg = 0; reg < 4; ++reg) {
      const int r = row0 + 4 * lq + reg;
      if (r < qlen) {
        const float lS = __logf(fmaxf(es[reg], 1e-30f));
        out[qstart + r]         = (float)par[reg];
        out[A + qstart + r]     = spa[reg] - m[reg] - lS;
        out[2 * A + qstart + r] = lS - ts[reg] / es[reg];
      }
    }
  }
}

extern "C" void kernel_launch(void* const* d_in, const int* in_sizes, int n_in,
                              void* d_out, int out_size, void* d_ws, size_t ws_size,
                              hipStream_t stream) {
  const float* x  = (const float*)d_in[0];
  const float* Wq = (const float*)d_in[1];
  const float* bq = (const float*)d_in[2];
  const float* Wk = (const float*)d_in[3];
  const float* bk = (const float*)d_in[4];
  const int* actors       = (const int*)d_in[5];
  const int* qindices     = (const int*)d_in[6];
  const int* actees       = (const int*)d_in[7];
  const int* kindices     = (const int*)d_in[8];
  const int* prev_actions = (const int*)d_in[9];

  const int A = in_sizes[5];
  const int E = in_sizes[7];
  const int B = (out_size - 3 * A) / ENVSTRIDE;
  if (B <= 0) return;

  unsigned* wfr_g = (unsigned*)d_ws;               // 32 KB packed W fragments
  int4* rng = (int4*)((char*)d_ws + 32768);        // B * 16 B env ranges

  ranges_kernel<<<dim3((B + 255) / 256), dim3(256), 0, stream>>>(qindices, kindices, A, E, B, rng);
  pack_w<<<dim3(16), dim3(256), 0, stream>>>(Wk, Wq, wfr_g);
  fused_env<<<dim3(B), dim3(256), 0, stream>>>(
      x, bq, bk, actors, qindices, actees, kindices, prev_actions,
      wfr_g, rng, A, E, (float*)d_out);
}

// Round 16
// 45.580 us; speedup vs baseline: 1.1513x; 1.1513x over previous
//
#include <hip/hip_runtime.h>
#include <math.h>

#define MA 64
#define ME 256
#define DM 256
#define DQK 32
#define ENVSTRIDE (MA * ME)            // 16384 floats per env
#define MASKVAL -998244352.0f          // bf16-rounded -1e9 (matches reference)
#define QK_SCALE 0.17677669529663687f  // 1/sqrt(32)
#define KSTR 40                        // LDS row stride in ushorts (80B)

typedef __attribute__((ext_vector_type(8))) short bf16x8;
typedef __attribute__((ext_vector_type(4))) float f32x4;
typedef unsigned short u16;

__device__ __forceinline__ int lb(const int* __restrict__ a, int n, int v){
  int lo = 0, hi = n;
  while (lo < hi){ int mid = (lo + hi) >> 1; if (a[mid] < v) lo = mid + 1; else hi = mid; }
  return lo;
}
// round-to-nearest-even f32 -> bf16 (validated rounds 8-15)
__device__ __forceinline__ unsigned pk2bf(float lo, float hi){
  unsigned ul = __float_as_uint(lo); ul = ul + 0x7FFFu + ((ul >> 16) & 1u);
  unsigned uh = __float_as_uint(hi); uh = uh + 0x7FFFu + ((uh >> 16) & 1u);
  return (ul >> 16) | (uh & 0xFFFF0000u);
}
__device__ __forceinline__ u16 f2bu(float f){
  unsigned u = __float_as_uint(f);
  return (u16)((u + 0x7FFFu + ((u >> 16) & 1u)) >> 16);
}

// ===== K0: pack Wk|Wq into bf16 MFMA-fragment order (layout validated r10-r15) =====
__global__ __launch_bounds__(256)
void pack_w(const float* __restrict__ Wk, const float* __restrict__ Wq,
            unsigned* __restrict__ wfr_g){
  const int base = blockIdx.x * 512 + threadIdx.x;
  #pragma unroll
  for (int ii = 0; ii < 2; ++ii) {
    const int i = base + ii * 256;
    const int p = i & 3, ln = (i >> 2) & 63, nt = (i >> 8) & 1, kk = (i >> 9) & 7, wh = i >> 12;
    const int k0  = kk * 32 + (ln >> 4) * 8 + 2 * p;
    const int col = nt * 16 + (ln & 15);
    const float* W = wh ? Wq : Wk;
    wfr_g[i] = pk2bf(W[(size_t)k0 * DQK + col], W[(size_t)(k0 + 1) * DQK + col]);
  }
}

// ===== K1: fused per-env kernel (r10 phases; W-frags in regs; 4 blocks/CU) =====
__global__ __launch_bounds__(256, 4)
void fused_env(const float* __restrict__ x,
               const float* __restrict__ bq, const float* __restrict__ bk,
               const int* __restrict__ actors, const int* __restrict__ qindices,
               const int* __restrict__ actees, const int* __restrict__ kindices,
               const int* __restrict__ prev_actions,
               const unsigned* __restrict__ wfr_g,
               int A, int E, float* __restrict__ out)
{
  __shared__ u16 kb[ME * KSTR];    // 20 KB bf16 keys
  __shared__ u16 qsm[MA * KSTR];   //  5 KB bf16 queries
  __shared__ int srange[4];

  const int t = threadIdx.x, b = blockIdx.x;
  if (t < 4) {
    const int* arr = (t < 2) ? qindices : kindices;
    const int nn = (t < 2) ? A : E;
    const int vv = (t == 0) ? b * MA : (t == 1) ? (b + 1) * MA
                 : (t == 2) ? b * ME : (b + 1) * ME;
    srange[t] = lb(arr, nn, vv);
  }
  __syncthreads();

  const int qstart = srange[0], qlen = srange[1] - srange[0];
  const int kstart = srange[2], klen = srange[3] - srange[2];

  const int lane = t & 63, w = t >> 6;
  const int lr = lane & 15, lq = lane >> 4;

  const int kt = (klen + 15) >> 4;
  const int qt = (qlen + 15) >> 4;
  const int ntiles = kt + qt;

  // ---- W fragments in registers; wave does K tiles then Q tiles -> at most one reload ----
  bf16x8 bfr[8][2];
  float bv0, bv1;
  bool qLoaded = (w >= kt);                // wave starts on Q tiles if it has no K tile
  {
    const unsigned* fb = wfr_g + (qLoaded ? 4096 : 0) + lane * 4;
    #pragma unroll
    for (int kk = 0; kk < 8; ++kk) {
      bfr[kk][0] = *(const bf16x8*)(fb + kk * 512);
      bfr[kk][1] = *(const bf16x8*)(fb + kk * 512 + 256);
    }
    bv0 = qLoaded ? bq[lr]      : bk[lr];
    bv1 = qLoaded ? bq[16 + lr] : bk[16 + lr];
  }

  // prefetch first tile's gather index
  int idxCur = 0;
  if (w < ntiles) {
    const bool isk = w < kt;
    const int rbase = (isk ? w : w - kt) << 4;
    const int len   = isk ? klen : qlen;
    const int* gi   = isk ? actees : actors;
    const int start = isk ? kstart : qstart;
    idxCur = gi[start + min(rbase + lr, len - 1)];
  }

  // ---- projection: merged K-then-Q tile list (datapath validated r9-r15) ----
  for (int i = w; i < ntiles; i += 4) {
    const bool isk = (i < kt);
    // prefetch next tile's gather index (breaks serial idx->x chain)
    int idxNext = 0;
    {
      const int inext = i + 4;
      if (inext < ntiles) {
        const bool nk = inext < kt;
        const int nrb = (nk ? inext : inext - kt) << 4;
        const int nlen = nk ? klen : qlen;
        const int* gi  = nk ? actees : actors;
        const int nst  = nk ? kstart : qstart;
        idxNext = gi[nst + min(nrb + lr, nlen - 1)];
      }
    }
    // one-time switch to Q fragments (wave-uniform branch)
    if (!isk && !qLoaded) {
      const unsigned* fb = wfr_g + 4096 + lane * 4;
      #pragma unroll
      for (int kk = 0; kk < 8; ++kk) {
        bfr[kk][0] = *(const bf16x8*)(fb + kk * 512);
        bfr[kk][1] = *(const bf16x8*)(fb + kk * 512 + 256);
      }
      bv0 = bq[lr]; bv1 = bq[16 + lr];
      qLoaded = true;
    }

    const int rbase = (isk ? i : i - kt) << 4;
    const int len   = isk ? klen : qlen;
    u16* dst        = isk ? kb : qsm;
    const float* xr = x + (size_t)idxCur * DM + lq * 8;

    f32x4 a0 = {bv0, bv0, bv0, bv0}, a1 = {bv1, bv1, bv1, bv1};
    #pragma unroll
    for (int h = 0; h < 2; ++h) {                  // half-tile chunks (r12-validated)
      float4 cx[8];
      #pragma unroll
      for (int k2 = 0; k2 < 4; ++k2) {
        cx[2*k2]   = *(const float4*)(xr + h * 128 + k2 * 32);
        cx[2*k2+1] = *(const float4*)(xr + h * 128 + k2 * 32 + 4);
      }
      #pragma unroll
      for (int k2 = 0; k2 < 4; ++k2) {
        const int kk = h * 4 + k2;
        union { unsigned u[4]; bf16x8 v; } fa;
        fa.u[0] = pk2bf(cx[2*k2].x,   cx[2*k2].y);
        fa.u[1] = pk2bf(cx[2*k2].z,   cx[2*k2].w);
        fa.u[2] = pk2bf(cx[2*k2+1].x, cx[2*k2+1].y);
        fa.u[3] = pk2bf(cx[2*k2+1].z, cx[2*k2+1].w);
        a0 = __builtin_amdgcn_mfma_f32_16x16x32_bf16(fa.v, bfr[kk][0], a0, 0, 0, 0);
        a1 = __builtin_amdgcn_mfma_f32_16x16x32_bf16(fa.v, bfr[kk][1], a1, 0, 0, 0);
      }
    }
    // D: col = lane&15, row = 4*(lane>>4)+reg (validated)
    #pragma unroll
    for (int reg = 0; reg < 4; ++reg) {
      const int row = rbase + 4 * lq + reg;
      if (row < len) {
        dst[row * KSTR + lr]      = f2bu(a0[reg]);
        dst[row * KSTR + 16 + lr] = f2bu(a1[reg]);
      }
    }
    idxCur = idxNext;
  }
  __syncthreads();

  // ---- logits + softmax: wave w owns q rows 16w..16w+15 (r10 verbatim) ----
  float* out_lg = out + (size_t)3 * A + (size_t)b * ENVSTRIDE;
  const int row0 = 16 * w;

  if (row0 >= qlen) {          // fully padded rows: MASKVAL fill
    const float4 mv = make_float4(MASKVAL, MASKVAL, MASKVAL, MASKVAL);
    float4* o4 = (float4*)out_lg;
    #pragma unroll
    for (int rr = 0; rr < 16; ++rr) o4[(row0 + rr) * 64 + lane] = mv;
    return;
  }

  const bf16x8 afr = *(const bf16x8*)&qsm[(row0 + lr) * KSTR + lq * 8];
  f32x4 acc[16];
  #pragma unroll
  for (int nt = 0; nt < 16; ++nt) {
    const bf16x8 bfr2 = *(const bf16x8*)&kb[(16 * nt + lr) * KSTR + lq * 8];
    f32x4 z = {0.f, 0.f, 0.f, 0.f};
    acc[nt] = __builtin_amdgcn_mfma_f32_16x16x32_bf16(afr, bfr2, z, 0, 0, 0);
  }

  int par[4];
  float m[4], spa[4], es[4], ts[4];
  #pragma unroll
  for (int reg = 0; reg < 4; ++reg) {
    const int r = row0 + 4 * lq + reg;
    par[reg] = (r < qlen) ? (prev_actions[qstart + r] & (ME - 1)) : -1;
    m[reg] = MASKVAL; spa[reg] = MASKVAL; es[reg] = 0.f; ts[reg] = 0.f;
  }

  #pragma unroll
  for (int nt = 0; nt < 16; ++nt) {
    const int col = 16 * nt + lr;
    const bool kv = (col < klen);
    #pragma unroll
    for (int reg = 0; reg < 4; ++reg) {
      const float d = kv ? acc[nt][reg] * QK_SCALE : MASKVAL;
      acc[nt][reg] = d;
      m[reg] = fmaxf(m[reg], d);
      if (col == par[reg]) spa[reg] = d;
    }
  }
  #pragma unroll
  for (int off = 1; off < 16; off <<= 1) {
    #pragma unroll
    for (int reg = 0; reg < 4; ++reg) {
      m[reg]   = fmaxf(m[reg],   __shfl_xor(m[reg],   off));
      spa[reg] = fmaxf(spa[reg], __shfl_xor(spa[reg], off));
    }
  }
  #pragma unroll
  for (int nt = 0; nt < 16; ++nt) {
    #pragma unroll
    for (int reg = 0; reg < 4; ++reg) {
      const float dd = acc[nt][reg] - m[reg];
      if (dd > -80.f) { const float e = __expf(dd); es[reg] += e; ts[reg] += e * dd; }
    }
  }
  #pragma unroll
  for (int off = 1; off < 16; off <<= 1) {
    #pragma unroll
    for (int reg = 0; reg < 4; ++reg) {
      es[reg] += __shfl_xor(es[reg], off);
      ts[reg] += __shfl_xor(ts[reg], off);
    }
  }

  #pragma unroll
  for (int nt = 0; nt < 16; ++nt) {
    #pragma unroll
    for (int reg = 0; reg < 4; ++reg) {
      const int r = row0 + 4 * lq + reg;
      out_lg[r * ME + 16 * nt + lr] = (r < qlen) ? acc[nt][reg] : MASKVAL;
    }
  }
  if (lr == 0) {
    #pragma unroll
    for (int reg = 0; reg < 4; ++reg) {
      const int r = row0 + 4 * lq + reg;
      if (r < qlen) {
        const float lS = __logf(fmaxf(es[reg], 1e-30f));
        out[qstart + r]         = (float)par[reg];
        out[A + qstart + r]     = spa[reg] - m[reg] - lS;
        out[2 * A + qstart + r] = lS - ts[reg] / es[reg];
      }
    }
  }
}

extern "C" void kernel_launch(void* const* d_in, const int* in_sizes, int n_in,
                              void* d_out, int out_size, void* d_ws, size_t ws_size,
                              hipStream_t stream) {
  const float* x  = (const float*)d_in[0];
  const float* Wq = (const float*)d_in[1];
  const float* bq = (const float*)d_in[2];
  const float* Wk = (const float*)d_in[3];
  const float* bk = (const float*)d_in[4];
  const int* actors       = (const int*)d_in[5];
  const int* qindices     = (const int*)d_in[6];
  const int* actees       = (const int*)d_in[7];
  const int* kindices     = (const int*)d_in[8];
  const int* prev_actions = (const int*)d_in[9];

  const int A = in_sizes[5];
  const int E = in_sizes[7];
  const int B = (out_size - 3 * A) / ENVSTRIDE;
  if (B <= 0) return;

  unsigned* wfr_g = (unsigned*)d_ws;   // 32 KB scratch for packed W fragments

  pack_w<<<dim3(16), dim3(256), 0, stream>>>(Wk, Wq, wfr_g);
  fused_env<<<dim3(B), dim3(256), 0, stream>>>(
      x, bq, bk, actors, qindices, actees, kindices, prev_actions,
      wfr_g, A, E, (float*)d_out);
}

// Round 18
// 40.076 us; speedup vs baseline: 1.3094x; 1.1373x over previous
//
#include <hip/hip_runtime.h>
#include <math.h>

#define MA 64
#define ME 256
#define DM 256
#define DQK 32
#define ENVSTRIDE (MA * ME)            // 16384 floats per env
#define MASKVAL -998244352.0f          // bf16-rounded -1e9 (matches reference)
#define QK_SCALE 0.17677669529663687f  // 1/sqrt(32)
#define KSTR 40                        // LDS row stride in ushorts (80B)

typedef __attribute__((ext_vector_type(8))) short bf16x8;
typedef __attribute__((ext_vector_type(4))) float f32x4;
typedef unsigned short u16;

__device__ __forceinline__ int lb(const int* __restrict__ a, int n, int v){
  int lo = 0, hi = n;
  while (lo < hi){ int mid = (lo + hi) >> 1; if (a[mid] < v) lo = mid + 1; else hi = mid; }
  return lo;
}
// round-to-nearest-even f32 -> bf16 (validated rounds 8-16)
__device__ __forceinline__ unsigned pk2bf(float lo, float hi){
  unsigned ul = __float_as_uint(lo); ul = ul + 0x7FFFu + ((ul >> 16) & 1u);
  unsigned uh = __float_as_uint(hi); uh = uh + 0x7FFFu + ((uh >> 16) & 1u);
  return (ul >> 16) | (uh & 0xFFFF0000u);
}
__device__ __forceinline__ u16 f2bu(float f){
  unsigned u = __float_as_uint(f);
  return (u16)((u + 0x7FFFu + ((u >> 16) & 1u)) >> 16);
}

// ===== fused per-env kernel: r10 champion verbatim + NON-TEMPORAL logits stores =====
__global__ __launch_bounds__(256)
void fused_env(const float* __restrict__ x,  const float* __restrict__ Wq, const float* __restrict__ bq,
               const float* __restrict__ Wk, const float* __restrict__ bk,
               const int* __restrict__ actors, const int* __restrict__ qindices,
               const int* __restrict__ actees, const int* __restrict__ kindices,
               const int* __restrict__ prev_actions, int A, int E, float* __restrict__ out)
{
  // W fragments pre-packed in MFMA order: [which][kk][nt][lane] bf16x8
  __shared__ __align__(16) unsigned wfr32[2 * 8 * 2 * 256];   // 32 KB
  __shared__ u16 kb[ME * KSTR];    // 20 KB bf16 keys
  __shared__ u16 qsm[MA * KSTR];   //  5 KB bf16 queries
  __shared__ int srange[4];

  const int t = threadIdx.x, b = blockIdx.x;
  if (t < 4) {
    const int* arr = (t < 2) ? qindices : kindices;
    const int nn = (t < 2) ? A : E;
    const int vv = (t == 0) ? b * MA : (t == 1) ? (b + 1) * MA
                 : (t == 2) ? b * ME : (b + 1) * ME;
    srange[t] = lb(arr, nn, vv);
  }

  // ---- cooperative W-fragment pack (one-time; validated layout rounds 8-16) ----
  #pragma unroll
  for (int ii = 0; ii < 32; ++ii) {
    const int i = t + ii * 256;
    const int p = i & 3, ln = (i >> 2) & 63, nt = (i >> 8) & 1, kk = (i >> 9) & 7, wh = i >> 12;
    const int k0  = kk * 32 + (ln >> 4) * 8 + 2 * p;
    const int col = nt * 16 + (ln & 15);
    const float* W = wh ? Wq : Wk;
    wfr32[i] = pk2bf(W[(size_t)k0 * DQK + col], W[(size_t)(k0 + 1) * DQK + col]);
  }
  __syncthreads();

  const int qstart = srange[0], qlen = srange[1] - srange[0];
  const int kstart = srange[2], klen = srange[3] - srange[2];

  const int lane = t & 63, w = t >> 6;
  const int lr = lane & 15, lq = lane >> 4;

  const float bkv0 = bk[lr], bkv1 = bk[16 + lr];
  const float bqv0 = bq[lr], bqv1 = bq[16 + lr];

  // ---- projection: merged K+Q tile list, wave-strided for balance ----
  const int kt = (klen + 15) >> 4;
  const int qt = (qlen + 15) >> 4;
  const int ntiles = kt + qt;

  for (int i = w; i < ntiles; i += 4) {
    const bool isk = (i < kt);
    const int  rbase = isk ? (i << 4) : ((i - kt) << 4);
    const int  len   = isk ? klen : qlen;
    const int  start = isk ? kstart : qstart;
    const int* gath  = isk ? actees : actors;
    u16*       dst   = isk ? kb : qsm;
    const unsigned* fbase = &wfr32[(isk ? 0 : 4096) + lane * 4];

    const int arow = start + min(rbase + lr, len - 1);
    const float* xr = x + (size_t)gath[arow] * DM + lq * 8;

    float4 cx[16];
    #pragma unroll
    for (int kk = 0; kk < 8; ++kk) {
      cx[2*kk]   = *(const float4*)(xr + kk * 32);
      cx[2*kk+1] = *(const float4*)(xr + kk * 32 + 4);
    }

    const float v0 = isk ? bkv0 : bqv0, v1 = isk ? bkv1 : bqv1;
    f32x4 a0 = {v0, v0, v0, v0}, a1 = {v1, v1, v1, v1};
    #pragma unroll
    for (int kk = 0; kk < 8; ++kk) {
      union { unsigned u[4]; bf16x8 v; } fa;
      fa.u[0] = pk2bf(cx[2*kk].x,   cx[2*kk].y);
      fa.u[1] = pk2bf(cx[2*kk].z,   cx[2*kk].w);
      fa.u[2] = pk2bf(cx[2*kk+1].x, cx[2*kk+1].y);
      fa.u[3] = pk2bf(cx[2*kk+1].z, cx[2*kk+1].w);
      const bf16x8 b0 = *(const bf16x8*)(fbase + kk * 512);
      const bf16x8 b1 = *(const bf16x8*)(fbase + kk * 512 + 256);
      a0 = __builtin_amdgcn_mfma_f32_16x16x32_bf16(fa.v, b0, a0, 0, 0, 0);
      a1 = __builtin_amdgcn_mfma_f32_16x16x32_bf16(fa.v, b1, a1, 0, 0, 0);
    }
    // D: col = lane&15, row = 4*(lane>>4)+reg (validated)
    #pragma unroll
    for (int reg = 0; reg < 4; ++reg) {
      const int row = rbase + 4 * lq + reg;
      if (row < len) {
        dst[row * KSTR + lr]      = f2bu(a0[reg]);
        dst[row * KSTR + 16 + lr] = f2bu(a1[reg]);
      }
    }
  }
  __syncthreads();

  // ---- logits + softmax: wave w owns q rows 16w..16w+15 (validated r9/r10) ----
  float* out_lg = out + (size_t)3 * A + (size_t)b * ENVSTRIDE;
  const int row0 = 16 * w;

  if (row0 >= qlen) {          // fully padded rows: MASKVAL fill (non-temporal, native vec type)
    const f32x4 mv = {MASKVAL, MASKVAL, MASKVAL, MASKVAL};
    f32x4* o4 = (f32x4*)out_lg;
    #pragma unroll
    for (int rr = 0; rr < 16; ++rr)
      __builtin_nontemporal_store(mv, &o4[(row0 + rr) * 64 + lane]);
    return;
  }

  const bf16x8 afr = *(const bf16x8*)&qsm[(row0 + lr) * KSTR + lq * 8];
  f32x4 acc[16];
  #pragma unroll
  for (int nt = 0; nt < 16; ++nt) {
    const bf16x8 bfr2 = *(const bf16x8*)&kb[(16 * nt + lr) * KSTR + lq * 8];
    f32x4 z = {0.f, 0.f, 0.f, 0.f};
    acc[nt] = __builtin_amdgcn_mfma_f32_16x16x32_bf16(afr, bfr2, z, 0, 0, 0);
  }

  int par[4];
  float m[4], spa[4], es[4], ts[4];
  #pragma unroll
  for (int reg = 0; reg < 4; ++reg) {
    const int r = row0 + 4 * lq + reg;
    par[reg] = (r < qlen) ? (prev_actions[qstart + r] & (ME - 1)) : -1;
    m[reg] = MASKVAL; spa[reg] = MASKVAL; es[reg] = 0.f; ts[reg] = 0.f;
  }

  #pragma unroll
  for (int nt = 0; nt < 16; ++nt) {
    const int col = 16 * nt + lr;
    const bool kv = (col < klen);
    #pragma unroll
    for (int reg = 0; reg < 4; ++reg) {
      const float d = kv ? acc[nt][reg] * QK_SCALE : MASKVAL;
      acc[nt][reg] = d;
      m[reg] = fmaxf(m[reg], d);
      if (col == par[reg]) spa[reg] = d;
    }
  }
  #pragma unroll
  for (int off = 1; off < 16; off <<= 1) {
    #pragma unroll
    for (int reg = 0; reg < 4; ++reg) {
      m[reg]   = fmaxf(m[reg],   __shfl_xor(m[reg],   off));
      spa[reg] = fmaxf(spa[reg], __shfl_xor(spa[reg], off));
    }
  }
  #pragma unroll
  for (int nt = 0; nt < 16; ++nt) {
    #pragma unroll
    for (int reg = 0; reg < 4; ++reg) {
      const float dd = acc[nt][reg] - m[reg];
      if (dd > -80.f) { const float e = __expf(dd); es[reg] += e; ts[reg] += e * dd; }
    }
  }
  #pragma unroll
  for (int off = 1; off < 16; off <<= 1) {
    #pragma unroll
    for (int reg = 0; reg < 4; ++reg) {
      es[reg] += __shfl_xor(es[reg], off);
      ts[reg] += __shfl_xor(ts[reg], off);
    }
  }

  // logits out (non-temporal: written once, never re-read by the GPU)
  #pragma unroll
  for (int nt = 0; nt < 16; ++nt) {
    #pragma unroll
    for (int reg = 0; reg < 4; ++reg) {
      const int r = row0 + 4 * lq + reg;
      const float v = (r < qlen) ? acc[nt][reg] : MASKVAL;
      __builtin_nontemporal_store(v, &out_lg[r * ME + 16 * nt + lr]);
    }
  }
  if (lr == 0) {
    #pragma unroll
    for (int reg = 0; reg < 4; ++reg) {
      const int r = row0 + 4 * lq + reg;
      if (r < qlen) {
        const float lS = __logf(fmaxf(es[reg], 1e-30f));
        out[qstart + r]         = (float)par[reg];
        out[A + qstart + r]     = spa[reg] - m[reg] - lS;
        out[2 * A + qstart + r] = lS - ts[reg] / es[reg];
      }
    }
  }
}

extern "C" void kernel_launch(void* const* d_in, const int* in_sizes, int n_in,
                              void* d_out, int out_size, void* d_ws, size_t ws_size,
                              hipStream_t stream) {
  const float* x  = (const float*)d_in[0];
  const float* Wq = (const float*)d_in[1];
  const float* bq = (const float*)d_in[2];
  const float* Wk = (const float*)d_in[3];
  const float* bk = (const float*)d_in[4];
  const int* actors       = (const int*)d_in[5];
  const int* qindices     = (const int*)d_in[6];
  const int* actees       = (const int*)d_in[7];
  const int* kindices     = (const int*)d_in[8];
  const int* prev_actions = (const int*)d_in[9];

  const int A = in_sizes[5];
  const int E = in_sizes[7];
  const int B = (out_size - 3 * A) / ENVSTRIDE;
  if (B <= 0) return;

  fused_env<<<dim3(B), dim3(256), 0, stream>>>(
      x, Wq, bq, Wk, bk, actors, qindices, actees, kindices, prev_actions,
      A, E, (float*)d_out);
}

// Round 19
// 39.754 us; speedup vs baseline: 1.3200x; 1.0081x over previous
//
#include <hip/hip_runtime.h>
#include <math.h>

#define MA 64
#define ME 256
#define DM 256
#define DQK 32
#define ENVSTRIDE (MA * ME)            // 16384 floats per env
#define MASKVAL -998244352.0f          // bf16-rounded -1e9 (matches reference)
#define QK_SCALE 0.17677669529663687f  // 1/sqrt(32)
#define KSTR 40                        // LDS row stride in ushorts (80B)

typedef __attribute__((ext_vector_type(8))) short bf16x8;
typedef __attribute__((ext_vector_type(4))) float f32x4;
typedef unsigned short u16;

__device__ __forceinline__ int lb(const int* __restrict__ a, int n, int v){
  int lo = 0, hi = n;
  while (lo < hi){ int mid = (lo + hi) >> 1; if (a[mid] < v) lo = mid + 1; else hi = mid; }
  return lo;
}
// round-to-nearest-even f32 -> bf16 (validated rounds 8-18)
__device__ __forceinline__ unsigned pk2bf(float lo, float hi){
  unsigned ul = __float_as_uint(lo); ul = ul + 0x7FFFu + ((ul >> 16) & 1u);
  unsigned uh = __float_as_uint(hi); uh = uh + 0x7FFFu + ((uh >> 16) & 1u);
  return (ul >> 16) | (uh & 0xFFFF0000u);
}
__device__ __forceinline__ u16 f2bu(float f){
  unsigned u = __float_as_uint(f);
  return (u16)((u + 0x7FFFu + ((u >> 16) & 1u)) >> 16);
}

// ===== fused per-env kernel: r18 champion + rolling gather-index prefetch (only change) =====
__global__ __launch_bounds__(256)
void fused_env(const float* __restrict__ x,  const float* __restrict__ Wq, const float* __restrict__ bq,
               const float* __restrict__ Wk, const float* __restrict__ bk,
               const int* __restrict__ actors, const int* __restrict__ qindices,
               const int* __restrict__ actees, const int* __restrict__ kindices,
               const int* __restrict__ prev_actions, int A, int E, float* __restrict__ out)
{
  // W fragments pre-packed in MFMA order: [which][kk][nt][lane] bf16x8
  __shared__ __align__(16) unsigned wfr32[2 * 8 * 2 * 256];   // 32 KB
  __shared__ u16 kb[ME * KSTR];    // 20 KB bf16 keys
  __shared__ u16 qsm[MA * KSTR];   //  5 KB bf16 queries
  __shared__ int srange[4];

  const int t = threadIdx.x, b = blockIdx.x;
  if (t < 4) {
    const int* arr = (t < 2) ? qindices : kindices;
    const int nn = (t < 2) ? A : E;
    const int vv = (t == 0) ? b * MA : (t == 1) ? (b + 1) * MA
                 : (t == 2) ? b * ME : (b + 1) * ME;
    srange[t] = lb(arr, nn, vv);
  }

  // ---- cooperative W-fragment pack (one-time; validated layout rounds 8-18) ----
  #pragma unroll
  for (int ii = 0; ii < 32; ++ii) {
    const int i = t + ii * 256;
    const int p = i & 3, ln = (i >> 2) & 63, nt = (i >> 8) & 1, kk = (i >> 9) & 7, wh = i >> 12;
    const int k0  = kk * 32 + (ln >> 4) * 8 + 2 * p;
    const int col = nt * 16 + (ln & 15);
    const float* W = wh ? Wq : Wk;
    wfr32[i] = pk2bf(W[(size_t)k0 * DQK + col], W[(size_t)(k0 + 1) * DQK + col]);
  }
  __syncthreads();

  const int qstart = srange[0], qlen = srange[1] - srange[0];
  const int kstart = srange[2], klen = srange[3] - srange[2];

  const int lane = t & 63, w = t >> 6;
  const int lr = lane & 15, lq = lane >> 4;

  const float bkv0 = bk[lr], bkv1 = bk[16 + lr];
  const float bqv0 = bq[lr], bqv1 = bq[16 + lr];

  // ---- projection: merged K+Q tile list, wave-strided for balance ----
  const int kt = (klen + 15) >> 4;
  const int qt = (qlen + 15) >> 4;
  const int ntiles = kt + qt;

  // prefetch first tile's gather index (breaks the idx->x serial chain; +1 VGPR)
  int idxCur = 0;
  if (w < ntiles) {
    const bool isk = w < kt;
    const int rbase = (isk ? w : w - kt) << 4;
    const int len   = isk ? klen : qlen;
    const int* gi   = isk ? actees : actors;
    const int start = isk ? kstart : qstart;
    idxCur = gi[start + min(rbase + lr, len - 1)];
  }

  for (int i = w; i < ntiles; i += 4) {
    const bool isk = (i < kt);
    const int  rbase = isk ? (i << 4) : ((i - kt) << 4);
    const int  len   = isk ? klen : qlen;
    u16*       dst   = isk ? kb : qsm;
    const unsigned* fbase = &wfr32[(isk ? 0 : 4096) + lane * 4];

    // issue next tile's index load now -> overlaps with this tile's pack/MFMA
    int idxNext = 0;
    {
      const int inext = i + 4;
      if (inext < ntiles) {
        const bool nk = inext < kt;
        const int nrb = (nk ? inext : inext - kt) << 4;
        const int nlen = nk ? klen : qlen;
        const int* gi  = nk ? actees : actors;
        const int nst  = nk ? kstart : qstart;
        idxNext = gi[nst + min(nrb + lr, nlen - 1)];
      }
    }

    const float* xr = x + (size_t)idxCur * DM + lq * 8;

    float4 cx[16];
    #pragma unroll
    for (int kk = 0; kk < 8; ++kk) {
      cx[2*kk]   = *(const float4*)(xr + kk * 32);
      cx[2*kk+1] = *(const float4*)(xr + kk * 32 + 4);
    }

    const float v0 = isk ? bkv0 : bqv0, v1 = isk ? bkv1 : bqv1;
    f32x4 a0 = {v0, v0, v0, v0}, a1 = {v1, v1, v1, v1};
    #pragma unroll
    for (int kk = 0; kk < 8; ++kk) {
      union { unsigned u[4]; bf16x8 v; } fa;
      fa.u[0] = pk2bf(cx[2*kk].x,   cx[2*kk].y);
      fa.u[1] = pk2bf(cx[2*kk].z,   cx[2*kk].w);
      fa.u[2] = pk2bf(cx[2*kk+1].x, cx[2*kk+1].y);
      fa.u[3] = pk2bf(cx[2*kk+1].z, cx[2*kk+1].w);
      const bf16x8 b0 = *(const bf16x8*)(fbase + kk * 512);
      const bf16x8 b1 = *(const bf16x8*)(fbase + kk * 512 + 256);
      a0 = __builtin_amdgcn_mfma_f32_16x16x32_bf16(fa.v, b0, a0, 0, 0, 0);
      a1 = __builtin_amdgcn_mfma_f32_16x16x32_bf16(fa.v, b1, a1, 0, 0, 0);
    }
    // D: col = lane&15, row = 4*(lane>>4)+reg (validated)
    #pragma unroll
    for (int reg = 0; reg < 4; ++reg) {
      const int row = rbase + 4 * lq + reg;
      if (row < len) {
        dst[row * KSTR + lr]      = f2bu(a0[reg]);
        dst[row * KSTR + 16 + lr] = f2bu(a1[reg]);
      }
    }
    idxCur = idxNext;
  }
  __syncthreads();

  // ---- logits + softmax: wave w owns q rows 16w..16w+15 (validated r9-r18) ----
  float* out_lg = out + (size_t)3 * A + (size_t)b * ENVSTRIDE;
  const int row0 = 16 * w;

  if (row0 >= qlen) {          // fully padded rows: MASKVAL fill (non-temporal)
    const f32x4 mv = {MASKVAL, MASKVAL, MASKVAL, MASKVAL};
    f32x4* o4 = (f32x4*)out_lg;
    #pragma unroll
    for (int rr = 0; rr < 16; ++rr)
      __builtin_nontemporal_store(mv, &o4[(row0 + rr) * 64 + lane]);
    return;
  }

  const bf16x8 afr = *(const bf16x8*)&qsm[(row0 + lr) * KSTR + lq * 8];
  f32x4 acc[16];
  #pragma unroll
  for (int nt = 0; nt < 16; ++nt) {
    const bf16x8 bfr2 = *(const bf16x8*)&kb[(16 * nt + lr) * KSTR + lq * 8];
    f32x4 z = {0.f, 0.f, 0.f, 0.f};
    acc[nt] = __builtin_amdgcn_mfma_f32_16x16x32_bf16(afr, bfr2, z, 0, 0, 0);
  }

  int par[4];
  float m[4], spa[4], es[4], ts[4];
  #pragma unroll
  for (int reg = 0; reg < 4; ++reg) {
    const int r = row0 + 4 * lq + reg;
    par[reg] = (r < qlen) ? (prev_actions[qstart + r] & (ME - 1)) : -1;
    m[reg] = MASKVAL; spa[reg] = MASKVAL; es[reg] = 0.f; ts[reg] = 0.f;
  }

  #pragma unroll
  for (int nt = 0; nt < 16; ++nt) {
    const int col = 16 * nt + lr;
    const bool kv = (col < klen);
    #pragma unroll
    for (int reg = 0; reg < 4; ++reg) {
      const float d = kv ? acc[nt][reg] * QK_SCALE : MASKVAL;
      acc[nt][reg] = d;
      m[reg] = fmaxf(m[reg], d);
      if (col == par[reg]) spa[reg] = d;
    }
  }
  #pragma unroll
  for (int off = 1; off < 16; off <<= 1) {
    #pragma unroll
    for (int reg = 0; reg < 4; ++reg) {
      m[reg]   = fmaxf(m[reg],   __shfl_xor(m[reg],   off));
      spa[reg] = fmaxf(spa[reg], __shfl_xor(spa[reg], off));
    }
  }
  #pragma unroll
  for (int nt = 0; nt < 16; ++nt) {
    #pragma unroll
    for (int reg = 0; reg < 4; ++reg) {
      const float dd = acc[nt][reg] - m[reg];
      if (dd > -80.f) { const float e = __expf(dd); es[reg] += e; ts[reg] += e * dd; }
    }
  }
  #pragma unroll
  for (int off = 1; off < 16; off <<= 1) {
    #pragma unroll
    for (int reg = 0; reg < 4; ++reg) {
      es[reg] += __shfl_xor(es[reg], off);
      ts[reg] += __shfl_xor(ts[reg], off);
    }
  }

  // logits out (non-temporal: written once, never re-read by the GPU)
  #pragma unroll
  for (int nt = 0; nt < 16; ++nt) {
    #pragma unroll
    for (int reg = 0; reg < 4; ++reg) {
      const int r = row0 + 4 * lq + reg;
      const float v = (r < qlen) ? acc[nt][reg] : MASKVAL;
      __builtin_nontemporal_store(v, &out_lg[r * ME + 16 * nt + lr]);
    }
  }
  if (lr == 0) {
    #pragma unroll
    for (int reg = 0; reg < 4; ++reg) {
      const int r = row0 + 4 * lq + reg;
      if (r < qlen) {
        const float lS = __logf(fmaxf(es[reg], 1e-30f));
        out[qstart + r]         = (float)par[reg];
        out[A + qstart + r]     = spa[reg] - m[reg] - lS;
        out[2 * A + qstart + r] = lS - ts[reg] / es[reg];
      }
    }
  }
}

extern "C" void kernel_launch(void* const* d_in, const int* in_sizes, int n_in,
                              void* d_out, int out_size, void* d_ws, size_t ws_size,
                              hipStream_t stream) {
  const float* x  = (const float*)d_in[0];
  const float* Wq = (const float*)d_in[1];
  const float* bq = (const float*)d_in[2];
  const float* Wk = (const float*)d_in[3];
  const float* bk = (const float*)d_in[4];
  const int* actors       = (const int*)d_in[5];
  const int* qindices     = (const int*)d_in[6];
  const int* actees       = (const int*)d_in[7];
  const int* kindices     = (const int*)d_in[8];
  const int* prev_actions = (const int*)d_in[9];

  const int A = in_sizes[5];
  const int E = in_sizes[7];
  const int B = (out_size - 3 * A) / ENVSTRIDE;
  if (B <= 0) return;

  fused_env<<<dim3(B), dim3(256), 0, stream>>>(
      x, Wq, bq, Wk, bk, actors, qindices, actees, kindices, prev_actions,
      A, E, (float*)d_out);
}